// Round 6
// baseline (1108.025 us; speedup 1.0000x reference)
//
#include <hip/hip_runtime.h>

#define S_LEN 2048
#define DIN   50
#define H     64

// tanh(v) = 1 - 2/(exp(2v)+1); ~1e-6 rel err, exact at +/-inf
__device__ __forceinline__ float tanh_fast(float v) {
    float e = __expf(2.0f * v);
    return 1.0f - 2.0f * __builtin_amdgcn_rcpf(e + 1.0f);
}

// Sum a value over the four 16-lane groups (result: every lane holds
// sum over kg of v[16*kg + (lane&15)]). Uses gfx950 permlane swaps
// (2 VALU instr + 2 adds, no LDS); sum is insensitive to swap direction.
__device__ __forceinline__ float sum4groups(float v) {
#if __has_builtin(__builtin_amdgcn_permlane16_swap) && __has_builtin(__builtin_amdgcn_permlane32_swap)
    typedef unsigned u2 __attribute__((ext_vector_type(2)));
    u2 r = __builtin_amdgcn_permlane16_swap(__float_as_uint(v), __float_as_uint(v), false, false);
    float s = __uint_as_float(r[0]) + __uint_as_float(r[1]);
    u2 t = __builtin_amdgcn_permlane32_swap(__float_as_uint(s), __float_as_uint(s), false, false);
    return __uint_as_float(t[0]) + __uint_as_float(t[1]);
#else
    v += __shfl_xor(v, 16, 64);
    v += __shfl_xor(v, 32, 64);
    return v;
#endif
}

__global__ __launch_bounds__(256, 2)
void rnn_fused(const float* __restrict__ x,
               const float* __restrict__ W_ih0, const float* __restrict__ W_hh0,
               const float* __restrict__ b_ih0, const float* __restrict__ b_hh0,
               const float* __restrict__ W_ih1, const float* __restrict__ W_hh1,
               const float* __restrict__ b_ih1, const float* __restrict__ b_hh1,
               const float* __restrict__ W1, const float* __restrict__ b1,
               const float* __restrict__ W2, const float* __restrict__ b2,
               float* __restrict__ out)
{
    const int b    = blockIdx.x;
    const int tid  = threadIdx.x;
    const int lane = tid & 63;
    const int w    = tid >> 6;      // output-chunk owner: outputs [16w, 16w+16)
    const int j    = lane & 15;     // output within chunk
    const int kg   = lane >> 4;     // k-group (4-way k-split within wave)
    const int outj = 16 * w + j;    // this lane's output unit

    __shared__ __align__(16) float xs[2][4][16];  // x row, 13-wide chunks padded to 16
    __shared__ __align__(16) float h1s[H];
    __shared__ __align__(16) float h2s[H];

    // ---- per-lane weights, register-resident (61 floats) ----
    float wx[13];
    #pragma unroll
    for (int i = 0; i < 13; ++i) {
        int c = 13 * kg + i;
        wx[i] = (c < DIN) ? W_ih0[outj * DIN + c] : 0.0f;
    }
    float whh0_l[16], wih1_l[16], whh1_l[16];
    #pragma unroll
    for (int i = 0; i < 16; ++i) {
        whh0_l[i] = W_hh0[outj * H + 16 * kg + i];
        wih1_l[i] = W_ih1[outj * H + 16 * kg + i];
        whh1_l[i] = W_hh1[outj * H + 16 * kg + i];
    }
    const float bias0 = b_ih0[outj] + b_hh0[outj];
    const float bias1 = b_ih1[outj] + b_hh1[outj];

    const float* __restrict__ xrow = x + (size_t)b * (size_t)(S_LEN * DIN);

    // staging slots (wave 0): slot (sw, sj) <- x[s*DIN + 13*sw + sj]
    const int  sw   = tid >> 4, sj = tid & 15;
    const int  scol = 13 * sw + sj;
    const bool sval = (tid < 64) && (sj < 13) && (scol < DIN);

    // stage row 0; prefetch rows 1, 2
    if (tid < 64) xs[0][sw][sj] = sval ? xrow[scol] : 0.0f;
    float pfA = sval ? xrow[1 * DIN + scol] : 0.0f;
    float pfB = sval ? xrow[2 * DIN + scol] : 0.0f;

    float h1c[16], h2c[16];    // h-state chunk kg, in registers
    #pragma unroll
    for (int i = 0; i < 16; ++i) { h1c[i] = 0.0f; h2c[i] = 0.0f; }

    __syncthreads();   // xs[0] visible

    // x-projection partial for s=0 (chunk kg)
    float xacc;
    {
        float a0 = 0, a1 = 0, a2 = 0, a3 = 0;
        #pragma unroll
        for (int q = 0; q < 3; ++q) {
            float4 xv = *(const float4*)&xs[0][kg][4 * q];
            a0 = fmaf(xv.x, wx[4 * q + 0], a0);
            a1 = fmaf(xv.y, wx[4 * q + 1], a1);
            a2 = fmaf(xv.z, wx[4 * q + 2], a2);
            a3 = fmaf(xv.w, wx[4 * q + 3], a3);
        }
        a0 = fmaf(xs[0][kg][12], wx[12], a0);
        xacc = (a0 + a1) + (a2 + a3);
    }

    for (int s = 0; s < S_LEN; ++s) {
        const int nb = (s + 1) & 1;

        // ---- stage 1: p1 = xacc + whh0-chunk . h1c (registers only) ----
        float a0 = xacc, a1 = 0, a2 = 0, a3 = 0;
        #pragma unroll
        for (int q = 0; q < 4; ++q) {
            a0 = fmaf(h1c[4 * q + 0], whh0_l[4 * q + 0], a0);
            a1 = fmaf(h1c[4 * q + 1], whh0_l[4 * q + 1], a1);
            a2 = fmaf(h1c[4 * q + 2], whh0_l[4 * q + 2], a2);
            a3 = fmaf(h1c[4 * q + 3], whh0_l[4 * q + 3], a3);
        }
        float h1n = tanh_fast(sum4groups((a0 + a1) + (a2 + a3)) + bias0);

        // independent filler: stage next x row, rotate prefetch
        if (tid < 64) xs[nb][sw][sj] = pfA;
        pfA = pfB;
        pfB = (sval && (s + 3) < S_LEN) ? xrow[(size_t)(s + 3) * DIN + scol] : 0.0f;

        // independent filler: stage-2 h2-part (uses last step's h2c regs)
        float c0 = 0, c1 = 0, c2 = 0, c3 = 0;
        #pragma unroll
        for (int q = 0; q < 4; ++q) {
            c0 = fmaf(h2c[4 * q + 0], whh1_l[4 * q + 0], c0);
            c1 = fmaf(h2c[4 * q + 1], whh1_l[4 * q + 1], c1);
            c2 = fmaf(h2c[4 * q + 2], whh1_l[4 * q + 2], c2);
            c3 = fmaf(h2c[4 * q + 3], whh1_l[4 * q + 3], c3);
        }

        if (kg == 0) h1s[16 * w + j] = h1n;
        __syncthreads();   // B1: h1_new + staged x visible

        // read h1_new chunk (4 broadcast b128; also h1_old for next step)
        float h1nc[16];
        #pragma unroll
        for (int q = 0; q < 4; ++q)
            *(float4*)&h1nc[4 * q] = *(const float4*)&h1s[16 * kg + 4 * q];

        // x-projection partial for s+1 (independent; fills ds_read bubble)
        float xn0 = 0, xn1 = 0, xn2 = 0, xn3 = 0;
        #pragma unroll
        for (int q = 0; q < 3; ++q) {
            float4 xv = *(const float4*)&xs[nb][kg][4 * q];
            xn0 = fmaf(xv.x, wx[4 * q + 0], xn0);
            xn1 = fmaf(xv.y, wx[4 * q + 1], xn1);
            xn2 = fmaf(xv.z, wx[4 * q + 2], xn2);
            xn3 = fmaf(xv.w, wx[4 * q + 3], xn3);
        }
        xn0 = fmaf(xs[nb][kg][12], wx[12], xn0);

        // ---- stage 2: h1-part ----
        #pragma unroll
        for (int q = 0; q < 4; ++q) {
            c0 = fmaf(h1nc[4 * q + 0], wih1_l[4 * q + 0], c0);
            c1 = fmaf(h1nc[4 * q + 1], wih1_l[4 * q + 1], c1);
            c2 = fmaf(h1nc[4 * q + 2], wih1_l[4 * q + 2], c2);
            c3 = fmaf(h1nc[4 * q + 3], wih1_l[4 * q + 3], c3);
        }
        float h2n = tanh_fast(sum4groups((c0 + c1) + (c2 + c3)) + bias1);

        if (kg == 0) h2s[16 * w + j] = h2n;
        __syncthreads();   // B2: h2_new visible

        // read h2 chunk for next step (off critical path: next use is post-B1)
        #pragma unroll
        for (int q = 0; q < 4; ++q)
            *(float4*)&h2c[4 * q] = *(const float4*)&h2s[16 * kg + 4 * q];

        #pragma unroll
        for (int i = 0; i < 16; ++i) h1c[i] = h1nc[i];
        xacc = (xn0 + xn1) + (xn2 + xn3);
    }

    // ---- head: relu(h2 @ W1^T + b1) -> sigmoid(. @ W2^T + b2) ----
    if (tid < 64) {
        float hv = 0.0f;
        if (lane < 32) {
            float acc = b1[lane];
            #pragma unroll
            for (int k = 0; k < H; ++k)
                acc = fmaf(h2s[k], W1[lane * H + k], acc);
            hv = fmaxf(acc, 0.0f) * W2[lane];
        }
        #pragma unroll
        for (int off = 32; off; off >>= 1)
            hv += __shfl_xor(hv, off, 64);
        if (lane == 0)
            out[b] = 1.0f / (1.0f + __expf(-(hv + b2[0])));
    }
}

extern "C" void kernel_launch(void* const* d_in, const int* in_sizes, int n_in,
                              void* d_out, int out_size, void* d_ws, size_t ws_size,
                              hipStream_t stream) {
    const float* x     = (const float*)d_in[0];
    const float* W_ih0 = (const float*)d_in[1];
    const float* W_hh0 = (const float*)d_in[2];
    const float* b_ih0 = (const float*)d_in[3];
    const float* b_hh0 = (const float*)d_in[4];
    const float* W_ih1 = (const float*)d_in[5];
    const float* W_hh1 = (const float*)d_in[6];
    const float* b_ih1 = (const float*)d_in[7];
    const float* b_hh1 = (const float*)d_in[8];
    const float* W1    = (const float*)d_in[9];
    const float* b1    = (const float*)d_in[10];
    const float* W2    = (const float*)d_in[11];
    const float* b2    = (const float*)d_in[12];
    float* out = (float*)d_out;

    rnn_fused<<<dim3(512), dim3(256), 0, stream>>>(
        x, W_ih0, W_hh0, b_ih0, b_hh0,
        W_ih1, W_hh1, b_ih1, b_hh1,
        W1, b1, W2, b2, out);
}

// Round 7
// 1063.822 us; speedup vs baseline: 1.0416x; 1.0416x over previous
//
#include <hip/hip_runtime.h>

#define S_LEN 2048
#define DIN   50
#define H     64

// tanh(v) = 1 - 2/(exp2(2*log2e*v)+1); ~1e-6 rel err, exact at +/-inf
__device__ __forceinline__ float tanh_fast(float v) {
    float e = __builtin_amdgcn_exp2f(v * 2.885390082f);   // exp(2v)
    return 1.0f - 2.0f * __builtin_amdgcn_rcpf(e + 1.0f);
}

// Sum over the four 16-lane groups (every lane ends with sum over kg of
// v[16*kg + (lane&15)]). Proven correct on this toolchain (R3/R6 passed).
__device__ __forceinline__ float sum4groups(float v) {
#if __has_builtin(__builtin_amdgcn_permlane16_swap) && __has_builtin(__builtin_amdgcn_permlane32_swap)
    typedef unsigned u2 __attribute__((ext_vector_type(2)));
    u2 r = __builtin_amdgcn_permlane16_swap(__float_as_uint(v), __float_as_uint(v), false, false);
    float s = __uint_as_float(r[0]) + __uint_as_float(r[1]);
    u2 t = __builtin_amdgcn_permlane32_swap(__float_as_uint(s), __float_as_uint(s), false, false);
    return __uint_as_float(t[0]) + __uint_as_float(t[1]);
#else
    v += __shfl_xor(v, 16, 64);
    v += __shfl_xor(v, 32, 64);
    return v;
#endif
}

__global__ __launch_bounds__(256)
__attribute__((amdgpu_waves_per_eu(2, 2)))   // grid = 2048 waves = exactly 2/EU: unlock 256 VGPRs
void rnn_fused(const float* __restrict__ x,
               const float* __restrict__ W_ih0, const float* __restrict__ W_hh0,
               const float* __restrict__ b_ih0, const float* __restrict__ b_hh0,
               const float* __restrict__ W_ih1, const float* __restrict__ W_hh1,
               const float* __restrict__ b_ih1, const float* __restrict__ b_hh1,
               const float* __restrict__ W1, const float* __restrict__ b1,
               const float* __restrict__ W2, const float* __restrict__ b2,
               float* __restrict__ out)
{
    const int b    = blockIdx.x;
    const int tid  = threadIdx.x;
    const int lane = tid & 63;
    const int w    = tid >> 6;      // output-chunk owner: outputs [16w, 16w+16)
    const int j    = lane & 15;     // output within chunk
    const int kg   = lane >> 4;     // k-group (4-way k-split within wave)
    const int outj = 16 * w + j;    // this lane's output unit

    __shared__ __align__(16) float xs[2][4][16];  // x row, 13-wide chunks padded to 16
    __shared__ __align__(16) float h1s[H];
    __shared__ __align__(16) float h2s[H];

    // ---- per-lane weights, register-resident (61 floats) ----
    float wx[13];
    #pragma unroll
    for (int i = 0; i < 13; ++i) {
        int c = 13 * kg + i;
        wx[i] = (c < DIN) ? W_ih0[outj * DIN + c] : 0.0f;
    }
    float whh0_l[16], wih1_l[16], whh1_l[16];
    #pragma unroll
    for (int i = 0; i < 16; ++i) {
        whh0_l[i] = W_hh0[outj * H + 16 * kg + i];
        wih1_l[i] = W_ih1[outj * H + 16 * kg + i];
        whh1_l[i] = W_hh1[outj * H + 16 * kg + i];
    }
    const float bias0 = b_ih0[outj] + b_hh0[outj];
    const float bias1 = b_ih1[outj] + b_hh1[outj];

    const float* __restrict__ xrow = x + (size_t)b * (size_t)(S_LEN * DIN);

    // staging slots (wave 0): slot (sw, sj) <- x[s*DIN + 13*sw + sj]
    const int  sw   = tid >> 4, sj = tid & 15;
    const int  scol = 13 * sw + sj;
    const bool sval = (tid < 64) && (sj < 13) && (scol < DIN);

    // stage row 0; prefetch rows 1, 2; incremented pointer (no per-step addr mul)
    if (tid < 64) xs[0][sw][sj] = sval ? xrow[scol] : 0.0f;
    float pfA = sval ? xrow[1 * DIN + scol] : 0.0f;
    float pfB = sval ? xrow[2 * DIN + scol] : 0.0f;
    const float* xpf = xrow + 3 * DIN + scol;

    float h1c[16], h2c[16];    // h-state chunk kg, registers (single-buffered)
    #pragma unroll
    for (int i = 0; i < 16; ++i) { h1c[i] = 0.0f; h2c[i] = 0.0f; }

    __syncthreads();   // xs[0] visible

    // x-projection partial for s=0 (chunk kg)
    float xacc;
    {
        float a0 = 0, a1 = 0, a2 = 0, a3 = 0;
        #pragma unroll
        for (int q = 0; q < 3; ++q) {
            float4 xv = *(const float4*)&xs[0][kg][4 * q];
            a0 = fmaf(xv.x, wx[4 * q + 0], a0);
            a1 = fmaf(xv.y, wx[4 * q + 1], a1);
            a2 = fmaf(xv.z, wx[4 * q + 2], a2);
            a3 = fmaf(xv.w, wx[4 * q + 3], a3);
        }
        a0 = fmaf(xs[0][kg][12], wx[12], a0);
        xacc = (a0 + a1) + (a2 + a3);
    }

    // One RNN step. CUR/NXT are literal LDS buffer indices; PFOK is the
    // uniform guard for prefetching row s+3.
#define STEP_BODY(CUR, NXT, PFOK)                                              \
    {                                                                          \
        /* stage 1: xacc + whh0-chunk . h1c (old) — registers only */          \
        float a0 = xacc, a1 = 0, a2 = 0, a3 = 0;                               \
        _Pragma("unroll")                                                      \
        for (int q = 0; q < 4; ++q) {                                          \
            a0 = fmaf(h1c[4 * q + 0], whh0_l[4 * q + 0], a0);                  \
            a1 = fmaf(h1c[4 * q + 1], whh0_l[4 * q + 1], a1);                  \
            a2 = fmaf(h1c[4 * q + 2], whh0_l[4 * q + 2], a2);                  \
            a3 = fmaf(h1c[4 * q + 3], whh0_l[4 * q + 3], a3);                  \
        }                                                                      \
        float h1n = tanh_fast(sum4groups((a0 + a1) + (a2 + a3)) + bias0);      \
        /* fillers: stage next x row, rotate prefetch */                       \
        if (tid < 64) xs[NXT][sw][sj] = pfA;                                   \
        pfA = pfB;                                                             \
        pfB = (sval && (PFOK)) ? *xpf : 0.0f;                                  \
        xpf += DIN;                                                            \
        /* filler: stage-2 h2-part (uses h2c from prev B2) */                  \
        float c0 = 0, c1 = 0, c2 = 0, c3 = 0;                                  \
        _Pragma("unroll")                                                      \
        for (int q = 0; q < 4; ++q) {                                          \
            c0 = fmaf(h2c[4 * q + 0], whh1_l[4 * q + 0], c0);                  \
            c1 = fmaf(h2c[4 * q + 1], whh1_l[4 * q + 1], c1);                  \
            c2 = fmaf(h2c[4 * q + 2], whh1_l[4 * q + 2], c2);                  \
            c3 = fmaf(h2c[4 * q + 3], whh1_l[4 * q + 3], c3);                  \
        }                                                                      \
        if (kg == 0) h1s[16 * w + j] = h1n;                                    \
        __syncthreads();   /* B1: h1_new + staged x visible */                 \
        /* reload h1 chunk in place (old h1c dead after stage 1) */            \
        _Pragma("unroll")                                                      \
        for (int q = 0; q < 4; ++q)                                            \
            *(float4*)&h1c[4 * q] = *(const float4*)&h1s[16 * kg + 4 * q];     \
        /* x-projection partial for next step (fills ds_read bubble) */        \
        float xn0 = 0, xn1 = 0, xn2 = 0, xn3 = 0;                              \
        _Pragma("unroll")                                                      \
        for (int q = 0; q < 3; ++q) {                                          \
            float4 xv = *(const float4*)&xs[NXT][kg][4 * q];                   \
            xn0 = fmaf(xv.x, wx[4 * q + 0], xn0);                              \
            xn1 = fmaf(xv.y, wx[4 * q + 1], xn1);                              \
            xn2 = fmaf(xv.z, wx[4 * q + 2], xn2);                              \
            xn3 = fmaf(xv.w, wx[4 * q + 3], xn3);                              \
        }                                                                      \
        xn0 = fmaf(xs[NXT][kg][12], wx[12], xn0);                              \
        /* stage 2: h1-part on fresh h1c */                                    \
        _Pragma("unroll")                                                      \
        for (int q = 0; q < 4; ++q) {                                          \
            c0 = fmaf(h1c[4 * q + 0], wih1_l[4 * q + 0], c0);                  \
            c1 = fmaf(h1c[4 * q + 1], wih1_l[4 * q + 1], c1);                  \
            c2 = fmaf(h1c[4 * q + 2], wih1_l[4 * q + 2], c2);                  \
            c3 = fmaf(h1c[4 * q + 3], wih1_l[4 * q + 3], c3);                  \
        }                                                                      \
        float h2n = tanh_fast(sum4groups((c0 + c1) + (c2 + c3)) + bias1);      \
        if (kg == 0) h2s[16 * w + j] = h2n;                                    \
        __syncthreads();   /* B2: h2_new visible */                            \
        _Pragma("unroll")                                                      \
        for (int q = 0; q < 4; ++q)                                            \
            *(float4*)&h2c[4 * q] = *(const float4*)&h2s[16 * kg + 4 * q];     \
        xacc = (xn0 + xn1) + (xn2 + xn3);                                      \
    }

    for (int s = 0; s < S_LEN; s += 2) {
        STEP_BODY(0, 1, s + 3 < S_LEN)
        STEP_BODY(1, 0, s + 4 < S_LEN)
    }
#undef STEP_BODY

    // ---- head: relu(h2 @ W1^T + b1) -> sigmoid(. @ W2^T + b2) ----
    if (tid < 64) {
        float hv = 0.0f;
        if (lane < 32) {
            float acc = b1[lane];
            #pragma unroll
            for (int k = 0; k < H; ++k)
                acc = fmaf(h2s[k], W1[lane * H + k], acc);
            hv = fmaxf(acc, 0.0f) * W2[lane];
        }
        #pragma unroll
        for (int off = 32; off; off >>= 1)
            hv += __shfl_xor(hv, off, 64);
        if (lane == 0)
            out[b] = 1.0f / (1.0f + __expf(-(hv + b2[0])));
    }
}

extern "C" void kernel_launch(void* const* d_in, const int* in_sizes, int n_in,
                              void* d_out, int out_size, void* d_ws, size_t ws_size,
                              hipStream_t stream) {
    const float* x     = (const float*)d_in[0];
    const float* W_ih0 = (const float*)d_in[1];
    const float* W_hh0 = (const float*)d_in[2];
    const float* b_ih0 = (const float*)d_in[3];
    const float* b_hh0 = (const float*)d_in[4];
    const float* W_ih1 = (const float*)d_in[5];
    const float* W_hh1 = (const float*)d_in[6];
    const float* b_ih1 = (const float*)d_in[7];
    const float* b_hh1 = (const float*)d_in[8];
    const float* W1    = (const float*)d_in[9];
    const float* b1    = (const float*)d_in[10];
    const float* W2    = (const float*)d_in[11];
    const float* b2    = (const float*)d_in[12];
    float* out = (float*)d_out;

    rnn_fused<<<dim3(512), dim3(256), 0, stream>>>(
        x, W_ih0, W_hh0, b_ih0, b_hh0,
        W_ih1, W_hh1, b_ih1, b_hh1,
        W1, b1, W2, b2, out);
}